// Round 1
// baseline (438.330 us; speedup 1.0000x reference)
//
#include <hip/hip_runtime.h>

// ---------------------------------------------------------------------------
// VectorQuantizer: z(16,32,32,256) fp32, embedding(256,8192), cluster_size(8192),
// embedding_avg(256,8192).
// Outputs (concat, fp32): quantize_st[4194304], diff[1], embed_ind[16384](as float),
// new_embedding[2097152], new_cluster_size[8192], new_embedding_avg[2097152]
//
// R6: argmin pipeline. R5's argmin serialized stage(64KB via global_load_lds +
// vmcnt(0) drain at __syncthreads) with compute (96 MFMA/wave) every kt-step:
// 193us ~= 99us MFMA floor + 90us staging, MfmaUtil 48%. R6 keeps the LDS
// single-buffered but stages through REGISTERS: prefetch kt+1 (32B/thread) as
// plain global loads during kt's compute, ds_write at top of next step. Raw
// s_barrier + manual lgkmcnt(0) (no vmcnt(0) drain) lets prefetch stay in
// flight across barriers. LDS image / MFMA order bit-identical to R4/R5.
// s_setprio(1) wraps the MFMA cluster (2 independent blocks/CU).
// All other kernels verbatim from R5.
// Aliasing timeline:
//   OUT_Q:      z_hi/z_lo planes (prep) -> quantize_st (gather)
//   OUT_NEWAVG: embsum [e][d] zeroed (prep), scattered (gather), read (fin1),
//               -> new_embedding_avg (fin2b)
//   OUT_NEWEMB: new_embedding (fin1), read by fin2b
// ---------------------------------------------------------------------------

#define DIMC  256
#define NEMB  8192
#define NROWS 16384

// d_out offsets (float elements)
#define OUT_Q      0u
#define OUT_DIFF   4194304u
#define OUT_IDX    4194305u
#define OUT_NEWEMB 4210689u
#define OUT_NEWCS  6307841u
#define OUT_NEWAVG 6316033u

// d_ws offsets (float elements) — total 2146308 floats = 8.59 MB
#define WS_EHI    0u          // bf16[8192][256] transposed emb hi
#define WS_ELO    1048576u    // bf16[8192][256] transposed emb lo
#define WS_COUNT  2097152u    // [NEMB]
#define WS_DIFF   2105344u    // [1]
#define WS_N      2105345u    // [1]  (written by prep, closed-form)
#define WS_ENORM  2105346u    // [NEMB] exact ||e||^2
#define WS_PACK   2113540u    // u64[NROWS]; byte 8454160 % 16 == 0 (16-aligned)

typedef __attribute__((ext_vector_type(8))) short short8;
typedef __attribute__((ext_vector_type(4))) float f32x4;

// round-to-nearest-even fp32 -> bf16 split: x ~= hi + lo
__device__ inline void split_bf16(float x, unsigned short& h, unsigned short& l) {
  unsigned u = __float_as_uint(x);
  unsigned r = u + 0x7FFFu + ((u >> 16) & 1u);
  h = (unsigned short)(r >> 16);
  float hf = __uint_as_float((unsigned)h << 16);
  float lo = x - hf;
  unsigned u2 = __float_as_uint(lo);
  unsigned r2 = u2 + 0x7FFFu + ((u2 >> 16) & 1u);
  l = (unsigned short)(r2 >> 16);
}

__device__ inline float bf16_f(unsigned short u) {
  return __uint_as_float((unsigned)u << 16);
}

// ---------------------------------------------------------------------------
// Fused prep: [0,1024) z split | [1024,1536) emb transpose/split |
// [1536,2048) embsum zero | [2048,2176) exact enorm | [2176,2184) pack 0xFF |
// [2184] count+diff zero | [2185] sum(cs) -> n closed-form
__global__ __launch_bounds__(256) void prep_kernel(
    const float* __restrict__ z, const float* __restrict__ emb,
    const float* __restrict__ cs, unsigned short* __restrict__ z_hi,
    unsigned short* __restrict__ z_lo, unsigned short* __restrict__ e_hi,
    unsigned short* __restrict__ e_lo, float* __restrict__ enorm,
    float* __restrict__ embsum, unsigned long long* __restrict__ pack,
    float* __restrict__ count_diff, float* __restrict__ n_out) {
  const int b = blockIdx.x;
  const int t = threadIdx.x;
  __shared__ float tile[64][68];
  __shared__ float red[4][64];

  if (b < 1024) {
#pragma unroll
    for (int it = 0; it < 4; ++it) {
      const int idx = (b * 256 + t) + it * 262144;
      const float4 v = reinterpret_cast<const float4*>(z)[idx];
      ushort4 h, l;
      split_bf16(v.x, h.x, l.x);
      split_bf16(v.y, h.y, l.y);
      split_bf16(v.z, h.z, l.z);
      split_bf16(v.w, h.w, l.w);
      reinterpret_cast<ushort4*>(z_hi)[idx] = h;
      reinterpret_cast<ushort4*>(z_lo)[idx] = l;
    }
  } else if (b < 1536) {
    const int bb = b - 1024;
    const int n0 = (bb & 127) * 64;
    const int k0 = (bb >> 7) * 64;
    const int c4 = (t & 15) * 4;
    const int rr = t >> 4;
#pragma unroll
    for (int i = 0; i < 4; ++i) {
      const int kl = rr + i * 16;
      const float4 v = *reinterpret_cast<const float4*>(
          &emb[(size_t)(k0 + kl) * NEMB + n0 + c4]);
      *reinterpret_cast<float4*>(&tile[kl][c4]) = v;
    }
    __syncthreads();
#pragma unroll
    for (int i = 0; i < 4; ++i) {
      const int nr = rr + i * 16;
      float4 v;
      v.x = tile[c4 + 0][nr];
      v.y = tile[c4 + 1][nr];
      v.z = tile[c4 + 2][nr];
      v.w = tile[c4 + 3][nr];
      const size_t off = (size_t)(n0 + nr) * DIMC + k0 + c4;
      ushort4 h, l;
      split_bf16(v.x, h.x, l.x);
      split_bf16(v.y, h.y, l.y);
      split_bf16(v.z, h.z, l.z);
      split_bf16(v.w, h.w, l.w);
      *reinterpret_cast<ushort4*>(&e_hi[off]) = h;
      *reinterpret_cast<ushort4*>(&e_lo[off]) = l;
    }
  } else if (b < 2048) {
    const int bb = b - 1536;
    const float4 zero = {0.f, 0.f, 0.f, 0.f};
#pragma unroll
    for (int it = 0; it < 4; ++it)
      reinterpret_cast<float4*>(embsum)[bb * 1024 + t + it * 256] = zero;
  } else if (b < 2176) {
    // exact enorm, R2 summation order
    const int l = t & 63;
    const int dg = t >> 6;
    const int e = (b - 2048) * 64 + l;
    float s = 0.f;
#pragma unroll 8
    for (int d = dg * 64; d < dg * 64 + 64; ++d) {
      const float v = emb[(size_t)d * NEMB + e];
      s = fmaf(v, v, s);
    }
    red[dg][l] = s;
    __syncthreads();
    if (dg == 0) enorm[e] = red[0][l] + red[1][l] + red[2][l] + red[3][l];
  } else if (b < 2184) {
    const int bb = b - 2176;
    const uint4 ff = {~0u, ~0u, ~0u, ~0u};  // ws_pack is 16-aligned
#pragma unroll
    for (int it = 0; it < 4; ++it)
      reinterpret_cast<uint4*>(pack)[bb * 1024 + t + it * 256] = ff;
  } else if (b == 2184) {
    for (int i = t; i < 8193; i += 256) count_diff[i] = 0.f;  // count + diff
  } else {
    // n = 0.99*sum(cs) + 0.01*16384 (sum(count) == NROWS exactly)
    float s = 0.f;
#pragma unroll
    for (int i = 0; i < 32; ++i) s += cs[t + i * 256];
#pragma unroll
    for (int off = 32; off > 0; off >>= 1) s += __shfl_down(s, off, 64);
    if ((t & 63) == 0) red[0][t >> 6] = s;
    __syncthreads();
    if (t == 0)
      n_out[0] = 0.99f * (red[0][0] + red[0][1] + red[0][2] + red[0][3]) +
                 163.84f;
  }
}

// ---------------------------------------------------------------------------
// MFMA dist+argmin — R6: reg-staged prefetch pipeline.
// Block 256 thr = 4 waves, tile 128 rows x 128 codes, wave tile 64x64
// (4x4 of 16x16x32 mfma), BK=64 dims (hi+lo = 128 shorts/row per slice),
// 3 mfma per (frag,kstep). Grid 512: bid>>2 = row-tile, bid&3 = code chunk
// (bid&3 == XCD-friendly: XCD x always sees chunk x&3 -> 2.1MB e-chunk L2-resident).
//
// Pipeline per kt-step s (s = nt*4+kt, 64 steps):
//   BARRIER_A            (LDS consumable; prev compute's ds_reads all consumed
//                         by MFMAs -> lgkm drained before barrier)
//   ds_write regs->LDS   (compiler inserts counted vmcnt for the staged loads)
//   issue loads for s+1  (plain global loads -> regs; stay in flight)
//   s_waitcnt lgkmcnt(0) (ds_writes visible)  — NO vmcnt(0) drain!
//   BARRIER_B
//   compute              (ds_read frags + 48 MFMA x2 ks, setprio(1) around MFMA)
// LDS image and MFMA accumulation order are bit-identical to R5.
__global__ __launch_bounds__(256, 2) void argmin_mfma_kernel(
    const unsigned short* __restrict__ z_hi, const unsigned short* __restrict__ z_lo,
    const unsigned short* __restrict__ e_hi, const unsigned short* __restrict__ e_lo,
    const float* __restrict__ enorm, unsigned long long* __restrict__ pack) {
  __shared__ short za[16384];  // 32 KB
  __shared__ short eb[16384];  // 32 KB
  const int tid = threadIdx.x;
  const int bid = blockIdx.x;
  const int r0 = (bid >> 2) * 128;
  const int ebase = (bid & 3) * 2048;
  const int tx = tid & 15;
  const int q = (tid >> 4) & 3;
  const int wave = tid >> 6;
  const int wm = wave & 1;   // row half
  const int wn = wave >> 1;  // col half

  // z_lo/e_lo are contiguous after z_hi/e_hi in their allocations; fold the
  // hi/lo select into a 32-bit element offset off a single base.
  const unsigned zdel = (unsigned)(z_lo - z_hi);  // 4194304
  const unsigned edel = (unsigned)(e_lo - e_hi);  // 2097152

  // Per-it source offsets (swizzled global addressing, same as R5's
  // global_load_lds sources). LDS dest chunk P = tid + it*256 -> &za[P*8].
  unsigned zo[8], eo[8];
#pragma unroll
  for (int it = 0; it < 8; ++it) {
    const int P = tid + it * 256;
    const int row = P >> 4;
    const int p = P & 15;
    const int o = (p & 7) ^ (row & 7);
    zo[it] = ((p & 8) ? zdel : 0u) + (unsigned)(r0 + row) * 256u + (unsigned)o * 8u;
    eo[it] = ((p & 8) ? edel : 0u) + (unsigned)row * 256u + (unsigned)o * 8u;
  }

  float rmin[4][4];
  int ridx[4][4];
#pragma unroll
  for (int i = 0; i < 4; ++i)
#pragma unroll
    for (int r = 0; r < 4; ++r) { rmin[i][r] = 3.4028235e38f; ridx[i][r] = 0; }

  // Prologue: stage s=0 (nt=0, kt=0 -> k0=0, n0=ebase) into regs.
  short8 pz[8], pe[8];
  {
    const unsigned n00 = (unsigned)ebase * 256u;
#pragma unroll
    for (int it = 0; it < 8; ++it) {
      pz[it] = *reinterpret_cast<const short8*>(z_hi + zo[it]);
      pe[it] = *reinterpret_cast<const short8*>(e_hi + eo[it] + n00);
    }
  }

  for (int nt = 0; nt < 16; ++nt) {
    const int n0 = ebase + nt * 128;
    f32x4 acc[4][4];
#pragma unroll
    for (int i = 0; i < 4; ++i)
#pragma unroll
      for (int j = 0; j < 4; ++j) acc[i][j] = (f32x4)0.0f;

    for (int kt = 0; kt < 4; ++kt) {
      // ---- barrier A: previous tile fully consumed by all waves ----
      asm volatile("" ::: "memory");
      __builtin_amdgcn_s_barrier();
      asm volatile("" ::: "memory");

      // ---- publish staged regs to LDS ----
#pragma unroll
      for (int it = 0; it < 8; ++it) {
        *reinterpret_cast<short8*>(&za[(tid + it * 256) * 8]) = pz[it];
        *reinterpret_cast<short8*>(&eb[(tid + it * 256) * 8]) = pe[it];
      }

      // ---- issue prefetch for step s+1 (in flight across barrier) ----
      const int s = nt * 4 + kt;
      if (s < 63) {
        const int s2 = s + 1;
        const unsigned k02 = (unsigned)(s2 & 3) * 64u;
        const unsigned n02 = (unsigned)(ebase + (s2 >> 2) * 128) * 256u + k02;
#pragma unroll
        for (int it = 0; it < 8; ++it) {
          pz[it] = *reinterpret_cast<const short8*>(z_hi + zo[it] + k02);
          pe[it] = *reinterpret_cast<const short8*>(e_hi + eo[it] + n02);
        }
      }

      // ---- barrier B: ds_writes visible; prefetch vmcnt NOT drained ----
      asm volatile("s_waitcnt lgkmcnt(0)" ::: "memory");
      __builtin_amdgcn_s_barrier();
      asm volatile("" ::: "memory");

      // ---- compute (R4 verbatim) ----
#pragma unroll
      for (int ks = 0; ks < 2; ++ks) {
        short8 ah[4], al[4], bh[4], bl[4];
#pragma unroll
        for (int i = 0; i < 4; ++i) {
          const int rl = wm * 64 + i * 16 + tx;
          const int oa = (ks * 4 + q) ^ (rl & 7);
          ah[i] = *reinterpret_cast<const short8*>(&za[rl * 128 + oa * 8]);
          al[i] = *reinterpret_cast<const short8*>(&za[rl * 128 + (oa + 8) * 8]);
          const int cl = wn * 64 + i * 16 + tx;
          const int ob = (ks * 4 + q) ^ (cl & 7);
          bh[i] = *reinterpret_cast<const short8*>(&eb[cl * 128 + ob * 8]);
          bl[i] = *reinterpret_cast<const short8*>(&eb[cl * 128 + (ob + 8) * 8]);
        }
        __builtin_amdgcn_s_setprio(1);
#pragma unroll
        for (int i = 0; i < 4; ++i)
#pragma unroll
          for (int j = 0; j < 4; ++j) {
            acc[i][j] = __builtin_amdgcn_mfma_f32_16x16x32_bf16(ah[i], bh[j],
                                                               acc[i][j], 0, 0, 0);
            acc[i][j] = __builtin_amdgcn_mfma_f32_16x16x32_bf16(ah[i], bl[j],
                                                               acc[i][j], 0, 0, 0);
            acc[i][j] = __builtin_amdgcn_mfma_f32_16x16x32_bf16(al[i], bh[j],
                                                               acc[i][j], 0, 0, 0);
          }
        __builtin_amdgcn_s_setprio(0);
      }
    }
    // epilogue: score = ||e||^2 - 2*dot, running first-min argmin.
#pragma unroll
    for (int j = 0; j < 4; ++j) {
      const int col = n0 + wn * 64 + j * 16 + tx;
      const float en = enorm[col];
#pragma unroll
      for (int i = 0; i < 4; ++i)
#pragma unroll
        for (int r = 0; r < 4; ++r) {
          const float s = en - 2.0f * acc[i][j][r];
          if (s < rmin[i][r]) { rmin[i][r] = s; ridx[i][r] = col; }
        }
    }
  }
#pragma unroll
  for (int i = 0; i < 4; ++i)
#pragma unroll
    for (int r = 0; r < 4; ++r) {
      float v = rmin[i][r];
      int ix = ridx[i][r];
#pragma unroll
      for (int off = 1; off < 16; off <<= 1) {
        const float ov = __shfl_xor(v, off, 16);
        const int oi = __shfl_xor(ix, off, 16);
        if (ov < v || (ov == v && oi < ix)) { v = ov; ix = oi; }
      }
      if (tx == 0) {
        const unsigned int fb = __float_as_uint(v);
        const unsigned int sb = (fb & 0x80000000u) ? ~fb : (fb | 0x80000000u);
        const unsigned long long key =
            ((unsigned long long)sb << 13) | (unsigned long long)(unsigned)ix;
        atomicMin(&pack[r0 + wm * 64 + i * 16 + q * 4 + r], key);
      }
    }
}

// ---------------------------------------------------------------------------
// Gather quantize (reconstruct fp32 = hi+lo), extract index, diff partial,
// scatter embed_sum/count. 1 wave per row. (R4 verbatim)
__global__ __launch_bounds__(256) void gather_update_kernel(
    const float* __restrict__ z, const unsigned short* __restrict__ e_hi,
    const unsigned short* __restrict__ e_lo,
    const unsigned long long* __restrict__ pack, float* __restrict__ out_q,
    float* __restrict__ out_idx, float* __restrict__ embsum,
    float* __restrict__ count, float* __restrict__ diff_acc) {
  const int row = blockIdx.x * 4 + (threadIdx.x >> 6);
  const int lane = threadIdx.x & 63;
  const int e = (int)(pack[row] & 8191ULL);
  if (lane == 0) out_idx[row] = (float)e;
  const float4 zv =
      *reinterpret_cast<const float4*>(&z[(size_t)row * DIMC + lane * 4]);
  const ushort4 h =
      *reinterpret_cast<const ushort4*>(&e_hi[(size_t)e * DIMC + lane * 4]);
  const ushort4 l =
      *reinterpret_cast<const ushort4*>(&e_lo[(size_t)e * DIMC + lane * 4]);
  const float q0 = bf16_f(h.x) + bf16_f(l.x);
  const float q1 = bf16_f(h.y) + bf16_f(l.y);
  const float q2 = bf16_f(h.z) + bf16_f(l.z);
  const float q3 = bf16_f(h.w) + bf16_f(l.w);
  const float d0 = q0 - zv.x, d1 = q1 - zv.y, d2 = q2 - zv.z, d3 = q3 - zv.w;
  float4 st;
  st.x = zv.x + d0; st.y = zv.y + d1; st.z = zv.z + d2; st.w = zv.w + d3;
  *reinterpret_cast<float4*>(&out_q[(size_t)row * DIMC + lane * 4]) = st;

  atomicAdd(&embsum[(size_t)e * DIMC + lane * 4 + 0], zv.x);
  atomicAdd(&embsum[(size_t)e * DIMC + lane * 4 + 1], zv.y);
  atomicAdd(&embsum[(size_t)e * DIMC + lane * 4 + 2], zv.z);
  atomicAdd(&embsum[(size_t)e * DIMC + lane * 4 + 3], zv.w);

  float local = d0 * d0 + d1 * d1 + d2 * d2 + d3 * d3;
#pragma unroll
  for (int off = 32; off > 0; off >>= 1) local += __shfl_down(local, off, 64);

  __shared__ float dred[4];
  if (lane == 0) {
    dred[threadIdx.x >> 6] = local;
    atomicAdd(&count[e], 1.0f);
  }
  __syncthreads();
  if (threadIdx.x == 0)
    atomicAdd(diff_acc, dred[0] + dred[1] + dred[2] + dred[3]);
}

// ---------------------------------------------------------------------------
// fin1: blocks [0,512): new_embedding[d][e] = (0.99*eavg + 0.01*embsum[e][d])
// * (1/smoothed(e)) — transpose + EMA + divide, one pass. smoothed recomputed
// locally from cs/count + closed-form n (no cross-kernel reduction).
// blocks [512,544): new_cluster_size + diff finalize.
__global__ __launch_bounds__(256) void fin1_kernel(
    const float* __restrict__ eavg, const float* __restrict__ embsum,
    const float* __restrict__ cs, const float* __restrict__ count,
    const float* __restrict__ n_ptr, const float* __restrict__ diff_acc,
    float* __restrict__ out_emb, float* __restrict__ out_ncs,
    float* __restrict__ out_diff) {
  const int b = blockIdx.x;
  const int t = threadIdx.x;
  __shared__ float tile[64][68];
  __shared__ float rs[64];
  if (b < 512) {
    const int e0 = (b & 127) * 64;
    const int d0 = (b >> 7) * 64;
    const int c4 = (t & 15) * 4;
    const int rr = t >> 4;
    if (t < 64) {
      const float n = n_ptr[0];
      const float ncs = cs[e0 + t] * 0.99f + 0.01f * count[e0 + t];
      const float sm = (ncs + 1e-5f) / (n + 0.08192f) * n;
      rs[t] = 1.0f / sm;
    }
#pragma unroll
    for (int i = 0; i < 4; ++i) {
      const int er = rr + i * 16;
      const float4 v = *reinterpret_cast<const float4*>(
          &embsum[(size_t)(e0 + er) * DIMC + d0 + c4]);
      *reinterpret_cast<float4*>(&tile[er][c4]) = v;
    }
    __syncthreads();
#pragma unroll
    for (int i = 0; i < 4; ++i) {
      const int dr = rr + i * 16;
      const size_t g = (size_t)(d0 + dr) * NEMB + e0 + c4;
      const float4 av = *reinterpret_cast<const float4*>(&eavg[g]);
      float4 o;
      o.x = (av.x * 0.99f + 0.01f * tile[c4 + 0][dr]) * rs[c4 + 0];
      o.y = (av.y * 0.99f + 0.01f * tile[c4 + 1][dr]) * rs[c4 + 1];
      o.z = (av.z * 0.99f + 0.01f * tile[c4 + 2][dr]) * rs[c4 + 2];
      o.w = (av.w * 0.99f + 0.01f * tile[c4 + 3][dr]) * rs[c4 + 3];
      *reinterpret_cast<float4*>(&out_emb[g]) = o;
    }
  } else {
    const int g = (b - 512) * 256 + t;
    out_ncs[g] = cs[g] * 0.99f + 0.01f * count[g];
    if (g == 0) out_diff[0] = diff_acc[0] * (1.0f / 4194304.0f);
  }
}

// ---------------------------------------------------------------------------
// fin2b: new_embedding_avg[g] = new_embedding[g] * smoothed(e). Elementwise —
// overwrites embsum scratch (fully consumed by fin1). ~2 ulp vs direct.
__global__ __launch_bounds__(256) void fin2b_kernel(
    const float* __restrict__ cs, const float* __restrict__ count,
    const float* __restrict__ n_ptr, const float* __restrict__ out_emb,
    float* __restrict__ out_avg) {
  const int g = blockIdx.x * 256 + threadIdx.x;
  const int e = g & 8191;
  const float n = n_ptr[0];
  const float ncs = cs[e] * 0.99f + 0.01f * count[e];
  const float sm = (ncs + 1e-5f) / (n + 0.08192f) * n;
  out_avg[g] = out_emb[g] * sm;
}

// ---------------------------------------------------------------------------
extern "C" void kernel_launch(void* const* d_in, const int* in_sizes, int n_in,
                              void* d_out, int out_size, void* d_ws,
                              size_t ws_size, hipStream_t stream) {
  const float* z = (const float*)d_in[0];
  const float* emb = (const float*)d_in[1];
  const float* cs = (const float*)d_in[2];
  const float* eavg = (const float*)d_in[3];
  float* out = (float*)d_out;
  float* ws = (float*)d_ws;

  unsigned short* e_hi = (unsigned short*)(ws + WS_EHI);
  unsigned short* e_lo = (unsigned short*)(ws + WS_ELO);
  float* ws_count = ws + WS_COUNT;
  float* ws_diff = ws + WS_DIFF;
  float* ws_n = ws + WS_N;
  float* ws_enorm = ws + WS_ENORM;
  unsigned long long* ws_pack = (unsigned long long*)(ws + WS_PACK);

  // d_out-aliased scratch (rewritten before readback):
  unsigned short* z_hi = (unsigned short*)(out + OUT_Q);
  unsigned short* z_lo = (unsigned short*)(out + OUT_Q + 2097152);
  float* embsum = out + OUT_NEWAVG;  // [e][d]

  prep_kernel<<<2186, 256, 0, stream>>>(z, emb, cs, z_hi, z_lo, e_hi, e_lo,
                                        ws_enorm, embsum, ws_pack, ws_count,
                                        ws_n);
  argmin_mfma_kernel<<<512, 256, 0, stream>>>(z_hi, z_lo, e_hi, e_lo, ws_enorm,
                                              ws_pack);
  gather_update_kernel<<<NROWS / 4, 256, 0, stream>>>(
      z, e_hi, e_lo, ws_pack, out + OUT_Q, out + OUT_IDX, embsum, ws_count,
      ws_diff);
  fin1_kernel<<<544, 256, 0, stream>>>(eavg, embsum, cs, ws_count, ws_n,
                                       ws_diff, out + OUT_NEWEMB,
                                       out + OUT_NEWCS, out + OUT_DIFF);
  fin2b_kernel<<<(DIMC * NEMB) / 256, 256, 0, stream>>>(
      cs, ws_count, ws_n, out + OUT_NEWEMB, out + OUT_NEWAVG);
}

// Round 2
// 403.162 us; speedup vs baseline: 1.0872x; 1.0872x over previous
//
#include <hip/hip_runtime.h>

// ---------------------------------------------------------------------------
// VectorQuantizer: z(16,32,32,256) fp32, embedding(256,8192), cluster_size(8192),
// embedding_avg(256,8192).
// Outputs (concat, fp32): quantize_st[4194304], diff[1], embed_ind[16384](as float),
// new_embedding[2097152], new_cluster_size[8192], new_embedding_avg[2097152]
//
// R7: argmin = T3 minimal 2-phase pipeline with DOUBLE-BUFFERED LDS and
// global_load_lds (no reg staging — R6's reg staging spilled to scratch:
// WRITE_SIZE 4->70MB, MfmaUtil 48->34). BK halved to 32 so the double buffer
// fits: 2 x (16KB za + 16KB eb) + 8KB enorm = 72KB -> still 2 blocks/CU.
// Per step s (128 steps): issue 8 global_load_lds for s+1 into buf[1-c];
// ds_read + 48 MFMA on buf[c]; ONE s_waitcnt vmcnt(0) lgkmcnt(0) + raw
// s_barrier at END of step (drain lands after a full compute phase -> load
// latency hidden; R5 drained immediately after issue = serialized).
// enorm staged to LDS at prologue so the nt-epilogue has zero vmem (keeps the
// compiler from draining the prefetch). K-slice order identical to R4/R5 ->
// bit-identical accumulation. LDS layout: 8 chunk-positions/row,
// phys = logical ^ (row&7) (hi=0..3, lo=4..7) — same bank spread as R5.
// All other kernels verbatim.
// Aliasing timeline:
//   OUT_Q:      z_hi/z_lo planes (prep) -> quantize_st (gather)
//   OUT_NEWAVG: embsum [e][d] zeroed (prep), scattered (gather), read (fin1),
//               -> new_embedding_avg (fin2b)
//   OUT_NEWEMB: new_embedding (fin1), read by fin2b
// ---------------------------------------------------------------------------

#define DIMC  256
#define NEMB  8192
#define NROWS 16384

// d_out offsets (float elements)
#define OUT_Q      0u
#define OUT_DIFF   4194304u
#define OUT_IDX    4194305u
#define OUT_NEWEMB 4210689u
#define OUT_NEWCS  6307841u
#define OUT_NEWAVG 6316033u

// d_ws offsets (float elements) — total 2146308 floats = 8.59 MB
#define WS_EHI    0u          // bf16[8192][256] transposed emb hi
#define WS_ELO    1048576u    // bf16[8192][256] transposed emb lo
#define WS_COUNT  2097152u    // [NEMB]
#define WS_DIFF   2105344u    // [1]
#define WS_N      2105345u    // [1]  (written by prep, closed-form)
#define WS_ENORM  2105346u    // [NEMB] exact ||e||^2
#define WS_PACK   2113540u    // u64[NROWS]; byte 8454160 % 16 == 0 (16-aligned)

typedef __attribute__((ext_vector_type(8))) short short8;
typedef __attribute__((ext_vector_type(4))) float f32x4;

// round-to-nearest-even fp32 -> bf16 split: x ~= hi + lo
__device__ inline void split_bf16(float x, unsigned short& h, unsigned short& l) {
  unsigned u = __float_as_uint(x);
  unsigned r = u + 0x7FFFu + ((u >> 16) & 1u);
  h = (unsigned short)(r >> 16);
  float hf = __uint_as_float((unsigned)h << 16);
  float lo = x - hf;
  unsigned u2 = __float_as_uint(lo);
  unsigned r2 = u2 + 0x7FFFu + ((u2 >> 16) & 1u);
  l = (unsigned short)(r2 >> 16);
}

__device__ inline float bf16_f(unsigned short u) {
  return __uint_as_float((unsigned)u << 16);
}

// ---------------------------------------------------------------------------
// Fused prep: [0,1024) z split | [1024,1536) emb transpose/split |
// [1536,2048) embsum zero | [2048,2176) exact enorm | [2176,2184) pack 0xFF |
// [2184] count+diff zero | [2185] sum(cs) -> n closed-form
__global__ __launch_bounds__(256) void prep_kernel(
    const float* __restrict__ z, const float* __restrict__ emb,
    const float* __restrict__ cs, unsigned short* __restrict__ z_hi,
    unsigned short* __restrict__ z_lo, unsigned short* __restrict__ e_hi,
    unsigned short* __restrict__ e_lo, float* __restrict__ enorm,
    float* __restrict__ embsum, unsigned long long* __restrict__ pack,
    float* __restrict__ count_diff, float* __restrict__ n_out) {
  const int b = blockIdx.x;
  const int t = threadIdx.x;
  __shared__ float tile[64][68];
  __shared__ float red[4][64];

  if (b < 1024) {
#pragma unroll
    for (int it = 0; it < 4; ++it) {
      const int idx = (b * 256 + t) + it * 262144;
      const float4 v = reinterpret_cast<const float4*>(z)[idx];
      ushort4 h, l;
      split_bf16(v.x, h.x, l.x);
      split_bf16(v.y, h.y, l.y);
      split_bf16(v.z, h.z, l.z);
      split_bf16(v.w, h.w, l.w);
      reinterpret_cast<ushort4*>(z_hi)[idx] = h;
      reinterpret_cast<ushort4*>(z_lo)[idx] = l;
    }
  } else if (b < 1536) {
    const int bb = b - 1024;
    const int n0 = (bb & 127) * 64;
    const int k0 = (bb >> 7) * 64;
    const int c4 = (t & 15) * 4;
    const int rr = t >> 4;
#pragma unroll
    for (int i = 0; i < 4; ++i) {
      const int kl = rr + i * 16;
      const float4 v = *reinterpret_cast<const float4*>(
          &emb[(size_t)(k0 + kl) * NEMB + n0 + c4]);
      *reinterpret_cast<float4*>(&tile[kl][c4]) = v;
    }
    __syncthreads();
#pragma unroll
    for (int i = 0; i < 4; ++i) {
      const int nr = rr + i * 16;
      float4 v;
      v.x = tile[c4 + 0][nr];
      v.y = tile[c4 + 1][nr];
      v.z = tile[c4 + 2][nr];
      v.w = tile[c4 + 3][nr];
      const size_t off = (size_t)(n0 + nr) * DIMC + k0 + c4;
      ushort4 h, l;
      split_bf16(v.x, h.x, l.x);
      split_bf16(v.y, h.y, l.y);
      split_bf16(v.z, h.z, l.z);
      split_bf16(v.w, h.w, l.w);
      *reinterpret_cast<ushort4*>(&e_hi[off]) = h;
      *reinterpret_cast<ushort4*>(&e_lo[off]) = l;
    }
  } else if (b < 2048) {
    const int bb = b - 1536;
    const float4 zero = {0.f, 0.f, 0.f, 0.f};
#pragma unroll
    for (int it = 0; it < 4; ++it)
      reinterpret_cast<float4*>(embsum)[bb * 1024 + t + it * 256] = zero;
  } else if (b < 2176) {
    // exact enorm, R2 summation order
    const int l = t & 63;
    const int dg = t >> 6;
    const int e = (b - 2048) * 64 + l;
    float s = 0.f;
#pragma unroll 8
    for (int d = dg * 64; d < dg * 64 + 64; ++d) {
      const float v = emb[(size_t)d * NEMB + e];
      s = fmaf(v, v, s);
    }
    red[dg][l] = s;
    __syncthreads();
    if (dg == 0) enorm[e] = red[0][l] + red[1][l] + red[2][l] + red[3][l];
  } else if (b < 2184) {
    const int bb = b - 2176;
    const uint4 ff = {~0u, ~0u, ~0u, ~0u};  // ws_pack is 16-aligned
#pragma unroll
    for (int it = 0; it < 4; ++it)
      reinterpret_cast<uint4*>(pack)[bb * 1024 + t + it * 256] = ff;
  } else if (b == 2184) {
    for (int i = t; i < 8193; i += 256) count_diff[i] = 0.f;  // count + diff
  } else {
    // n = 0.99*sum(cs) + 0.01*16384 (sum(count) == NROWS exactly)
    float s = 0.f;
#pragma unroll
    for (int i = 0; i < 32; ++i) s += cs[t + i * 256];
#pragma unroll
    for (int off = 32; off > 0; off >>= 1) s += __shfl_down(s, off, 64);
    if ((t & 63) == 0) red[0][t >> 6] = s;
    __syncthreads();
    if (t == 0)
      n_out[0] = 0.99f * (red[0][0] + red[0][1] + red[0][2] + red[0][3]) +
                 163.84f;
  }
}

// ---------------------------------------------------------------------------
// MFMA dist+argmin — R7: double-buffered LDS, BK=32, global_load_lds,
// one barrier + one vmcnt(0) per step (issued a full compute phase after the
// loads -> hidden). Block 256 thr = 4 waves, tile 128 rows x 128 codes,
// wave tile 64x64 (4x4 of 16x16x32 mfma), 48 MFMA/wave/step, 128 steps.
// Grid 512: bid>>2 = row-tile, bid&3 = code chunk.
// LDS half-buffer layout (za/eb identical): [128 rows][8 chunks][8 shorts],
// logical chunk L (0..3 = hi dims L*8.., 4..7 = lo dims (L-4)*8..) stored at
// physical position L ^ (row&7). K-slice order across steps == R4/R5 ->
// bit-identical accumulation.
__global__ __launch_bounds__(256, 2) void argmin_mfma_kernel(
    const unsigned short* __restrict__ z_hi, const unsigned short* __restrict__ z_lo,
    const unsigned short* __restrict__ e_hi, const unsigned short* __restrict__ e_lo,
    const float* __restrict__ enorm, unsigned long long* __restrict__ pack) {
  __shared__ short za[16384];   // 2 x 16 KB
  __shared__ short eb[16384];   // 2 x 16 KB
  __shared__ float elds[2048];  // 8 KB: ||e||^2 for this code chunk
  const int tid = threadIdx.x;
  const int bid = blockIdx.x;
  const int r0 = (bid >> 2) * 128;
  const int ebase = (bid & 3) * 2048;
  const int tx = tid & 15;
  const int q = (tid >> 4) & 3;
  const int wave = tid >> 6;
  const int wm = wave & 1;   // row half
  const int wn = wave >> 1;  // col half

  // hi/lo planes are contiguous; fold select into an element offset.
  const unsigned zdel = (unsigned)(z_lo - z_hi);  // 4194304
  const unsigned edel = (unsigned)(e_lo - e_hi);  // 2097152

  // Staging role of this thread (constant across steps): for chunk
  // P = tid + it*256: row = (tid>>3) + it*32, phys pos p = tid&7,
  // logical chunk lp = p ^ (row&7)  (same for all it since row&7 == (tid>>3)&7).
  const int lp = (tid & 7) ^ ((tid >> 3) & 7);
  const unsigned sz = (lp & 4) ? zdel : 0u;
  const unsigned se = (lp & 4) ? edel : 0u;
  const unsigned dch8 = (unsigned)(lp & 3) * 8u;
  unsigned zo[4], eo[4];
#pragma unroll
  for (int it = 0; it < 4; ++it) {
    const int row_it = (tid >> 3) + it * 32;
    zo[it] = sz + (unsigned)(r0 + row_it) * 256u + dch8;
    eo[it] = se + (unsigned)(ebase + row_it) * 256u + dch8;
  }

  // Issue 8 global_load_lds for step sidx into buffer sidx&1.
  auto STAGE = [&](int sidx) {
    const unsigned k0s = (unsigned)(sidx & 7) * 32u;
    const unsigned eas = (unsigned)(sidx >> 3) * 32768u + k0s;
    const unsigned lb = (unsigned)(sidx & 1) * 8192u + (unsigned)tid * 8u;
#pragma unroll
    for (int it = 0; it < 4; ++it) {
      __builtin_amdgcn_global_load_lds(
          (const __attribute__((address_space(1))) unsigned int*)(z_hi + zo[it] + k0s),
          (__attribute__((address_space(3))) unsigned int*)&za[lb + it * 2048],
          16, 0, 0);
      __builtin_amdgcn_global_load_lds(
          (const __attribute__((address_space(1))) unsigned int*)(e_hi + eo[it] + eas),
          (__attribute__((address_space(3))) unsigned int*)&eb[lb + it * 2048],
          16, 0, 0);
    }
  };

  float rmin[4][4];
  int ridx[4][4];
#pragma unroll
  for (int i = 0; i < 4; ++i)
#pragma unroll
    for (int r = 0; r < 4; ++r) { rmin[i][r] = 3.4028235e38f; ridx[i][r] = 0; }

  // Prologue: loads for step 0 in flight, enorm chunk -> LDS, full drain.
  STAGE(0);
  {
    const float4 v0 = *reinterpret_cast<const float4*>(&enorm[ebase + tid * 8]);
    const float4 v1 =
        *reinterpret_cast<const float4*>(&enorm[ebase + tid * 8 + 4]);
    *reinterpret_cast<float4*>(&elds[tid * 8]) = v0;
    *reinterpret_cast<float4*>(&elds[tid * 8 + 4]) = v1;
  }
  __syncthreads();

  for (int nt = 0; nt < 16; ++nt) {
    f32x4 acc[4][4];
#pragma unroll
    for (int i = 0; i < 4; ++i)
#pragma unroll
      for (int j = 0; j < 4; ++j) acc[i][j] = (f32x4)0.0f;

    for (int k2 = 0; k2 < 8; ++k2) {
      const int s = nt * 8 + k2;
      // ---- issue prefetch for s+1 into the other buffer ----
      if (s < 127) STAGE(s + 1);

      // ---- compute on buffer s&1 (data drained at end of prev step) ----
      const short* zb = &za[(unsigned)(s & 1) * 8192u];
      const short* ebf = &eb[(unsigned)(s & 1) * 8192u];
      short8 ah[4], al[4], bh[4], bl[4];
#pragma unroll
      for (int i = 0; i < 4; ++i) {
        const int va = q ^ (tx & 7);
        const int rl = wm * 64 + i * 16 + tx;
        ah[i] = *reinterpret_cast<const short8*>(&zb[rl * 64 + va * 8]);
        al[i] = *reinterpret_cast<const short8*>(&zb[rl * 64 + (va ^ 4) * 8]);
        const int cl = wn * 64 + i * 16 + tx;
        bh[i] = *reinterpret_cast<const short8*>(&ebf[cl * 64 + va * 8]);
        bl[i] = *reinterpret_cast<const short8*>(&ebf[cl * 64 + (va ^ 4) * 8]);
      }
#pragma unroll
      for (int i = 0; i < 4; ++i)
#pragma unroll
        for (int j = 0; j < 4; ++j) {
          acc[i][j] = __builtin_amdgcn_mfma_f32_16x16x32_bf16(ah[i], bh[j],
                                                             acc[i][j], 0, 0, 0);
          acc[i][j] = __builtin_amdgcn_mfma_f32_16x16x32_bf16(ah[i], bl[j],
                                                             acc[i][j], 0, 0, 0);
          acc[i][j] = __builtin_amdgcn_mfma_f32_16x16x32_bf16(al[i], bh[j],
                                                             acc[i][j], 0, 0, 0);
        }

      // ---- end-of-step: drain prefetch (issued a full compute phase ago)
      //      + all LDS reads, then barrier. No mid-step drains. ----
      asm volatile("s_waitcnt vmcnt(0) lgkmcnt(0)" ::: "memory");
      __builtin_amdgcn_sched_barrier(0);
      __builtin_amdgcn_s_barrier();
      asm volatile("" ::: "memory");
    }

    // nt epilogue: score = ||e||^2 - 2*dot (enorm from LDS — no vmem).
#pragma unroll
    for (int j = 0; j < 4; ++j) {
      const int cidx = nt * 128 + wn * 64 + j * 16 + tx;
      const float en = elds[cidx];
      const int col = ebase + cidx;
#pragma unroll
      for (int i = 0; i < 4; ++i)
#pragma unroll
        for (int r = 0; r < 4; ++r) {
          const float sc = en - 2.0f * acc[i][j][r];
          if (sc < rmin[i][r]) { rmin[i][r] = sc; ridx[i][r] = col; }
        }
    }
  }

#pragma unroll
  for (int i = 0; i < 4; ++i)
#pragma unroll
    for (int r = 0; r < 4; ++r) {
      float v = rmin[i][r];
      int ix = ridx[i][r];
#pragma unroll
      for (int off = 1; off < 16; off <<= 1) {
        const float ov = __shfl_xor(v, off, 16);
        const int oi = __shfl_xor(ix, off, 16);
        if (ov < v || (ov == v && oi < ix)) { v = ov; ix = oi; }
      }
      if (tx == 0) {
        const unsigned int fb = __float_as_uint(v);
        const unsigned int sb = (fb & 0x80000000u) ? ~fb : (fb | 0x80000000u);
        const unsigned long long key =
            ((unsigned long long)sb << 13) | (unsigned long long)(unsigned)ix;
        atomicMin(&pack[r0 + wm * 64 + i * 16 + q * 4 + r], key);
      }
    }
}

// ---------------------------------------------------------------------------
// Gather quantize (reconstruct fp32 = hi+lo), extract index, diff partial,
// scatter embed_sum/count. 1 wave per row. (R4 verbatim)
__global__ __launch_bounds__(256) void gather_update_kernel(
    const float* __restrict__ z, const unsigned short* __restrict__ e_hi,
    const unsigned short* __restrict__ e_lo,
    const unsigned long long* __restrict__ pack, float* __restrict__ out_q,
    float* __restrict__ out_idx, float* __restrict__ embsum,
    float* __restrict__ count, float* __restrict__ diff_acc) {
  const int row = blockIdx.x * 4 + (threadIdx.x >> 6);
  const int lane = threadIdx.x & 63;
  const int e = (int)(pack[row] & 8191ULL);
  if (lane == 0) out_idx[row] = (float)e;
  const float4 zv =
      *reinterpret_cast<const float4*>(&z[(size_t)row * DIMC + lane * 4]);
  const ushort4 h =
      *reinterpret_cast<const ushort4*>(&e_hi[(size_t)e * DIMC + lane * 4]);
  const ushort4 l =
      *reinterpret_cast<const ushort4*>(&e_lo[(size_t)e * DIMC + lane * 4]);
  const float q0 = bf16_f(h.x) + bf16_f(l.x);
  const float q1 = bf16_f(h.y) + bf16_f(l.y);
  const float q2 = bf16_f(h.z) + bf16_f(l.z);
  const float q3 = bf16_f(h.w) + bf16_f(l.w);
  const float d0 = q0 - zv.x, d1 = q1 - zv.y, d2 = q2 - zv.z, d3 = q3 - zv.w;
  float4 st;
  st.x = zv.x + d0; st.y = zv.y + d1; st.z = zv.z + d2; st.w = zv.w + d3;
  *reinterpret_cast<float4*>(&out_q[(size_t)row * DIMC + lane * 4]) = st;

  atomicAdd(&embsum[(size_t)e * DIMC + lane * 4 + 0], zv.x);
  atomicAdd(&embsum[(size_t)e * DIMC + lane * 4 + 1], zv.y);
  atomicAdd(&embsum[(size_t)e * DIMC + lane * 4 + 2], zv.z);
  atomicAdd(&embsum[(size_t)e * DIMC + lane * 4 + 3], zv.w);

  float local = d0 * d0 + d1 * d1 + d2 * d2 + d3 * d3;
#pragma unroll
  for (int off = 32; off > 0; off >>= 1) local += __shfl_down(local, off, 64);

  __shared__ float dred[4];
  if (lane == 0) {
    dred[threadIdx.x >> 6] = local;
    atomicAdd(&count[e], 1.0f);
  }
  __syncthreads();
  if (threadIdx.x == 0)
    atomicAdd(diff_acc, dred[0] + dred[1] + dred[2] + dred[3]);
}

// ---------------------------------------------------------------------------
// fin1: blocks [0,512): new_embedding[d][e] = (0.99*eavg + 0.01*embsum[e][d])
// * (1/smoothed(e)) — transpose + EMA + divide, one pass. smoothed recomputed
// locally from cs/count + closed-form n (no cross-kernel reduction).
// blocks [512,544): new_cluster_size + diff finalize.
__global__ __launch_bounds__(256) void fin1_kernel(
    const float* __restrict__ eavg, const float* __restrict__ embsum,
    const float* __restrict__ cs, const float* __restrict__ count,
    const float* __restrict__ n_ptr, const float* __restrict__ diff_acc,
    float* __restrict__ out_emb, float* __restrict__ out_ncs,
    float* __restrict__ out_diff) {
  const int b = blockIdx.x;
  const int t = threadIdx.x;
  __shared__ float tile[64][68];
  __shared__ float rs[64];
  if (b < 512) {
    const int e0 = (b & 127) * 64;
    const int d0 = (b >> 7) * 64;
    const int c4 = (t & 15) * 4;
    const int rr = t >> 4;
    if (t < 64) {
      const float n = n_ptr[0];
      const float ncs = cs[e0 + t] * 0.99f + 0.01f * count[e0 + t];
      const float sm = (ncs + 1e-5f) / (n + 0.08192f) * n;
      rs[t] = 1.0f / sm;
    }
#pragma unroll
    for (int i = 0; i < 4; ++i) {
      const int er = rr + i * 16;
      const float4 v = *reinterpret_cast<const float4*>(
          &embsum[(size_t)(e0 + er) * DIMC + d0 + c4]);
      *reinterpret_cast<float4*>(&tile[er][c4]) = v;
    }
    __syncthreads();
#pragma unroll
    for (int i = 0; i < 4; ++i) {
      const int dr = rr + i * 16;
      const size_t g = (size_t)(d0 + dr) * NEMB + e0 + c4;
      const float4 av = *reinterpret_cast<const float4*>(&eavg[g]);
      float4 o;
      o.x = (av.x * 0.99f + 0.01f * tile[c4 + 0][dr]) * rs[c4 + 0];
      o.y = (av.y * 0.99f + 0.01f * tile[c4 + 1][dr]) * rs[c4 + 1];
      o.z = (av.z * 0.99f + 0.01f * tile[c4 + 2][dr]) * rs[c4 + 2];
      o.w = (av.w * 0.99f + 0.01f * tile[c4 + 3][dr]) * rs[c4 + 3];
      *reinterpret_cast<float4*>(&out_emb[g]) = o;
    }
  } else {
    const int g = (b - 512) * 256 + t;
    out_ncs[g] = cs[g] * 0.99f + 0.01f * count[g];
    if (g == 0) out_diff[0] = diff_acc[0] * (1.0f / 4194304.0f);
  }
}

// ---------------------------------------------------------------------------
// fin2b: new_embedding_avg[g] = new_embedding[g] * smoothed(e). Elementwise —
// overwrites embsum scratch (fully consumed by fin1). ~2 ulp vs direct.
__global__ __launch_bounds__(256) void fin2b_kernel(
    const float* __restrict__ cs, const float* __restrict__ count,
    const float* __restrict__ n_ptr, const float* __restrict__ out_emb,
    float* __restrict__ out_avg) {
  const int g = blockIdx.x * 256 + threadIdx.x;
  const int e = g & 8191;
  const float n = n_ptr[0];
  const float ncs = cs[e] * 0.99f + 0.01f * count[e];
  const float sm = (ncs + 1e-5f) / (n + 0.08192f) * n;
  out_avg[g] = out_emb[g] * sm;
}

// ---------------------------------------------------------------------------
extern "C" void kernel_launch(void* const* d_in, const int* in_sizes, int n_in,
                              void* d_out, int out_size, void* d_ws,
                              size_t ws_size, hipStream_t stream) {
  const float* z = (const float*)d_in[0];
  const float* emb = (const float*)d_in[1];
  const float* cs = (const float*)d_in[2];
  const float* eavg = (const float*)d_in[3];
  float* out = (float*)d_out;
  float* ws = (float*)d_ws;

  unsigned short* e_hi = (unsigned short*)(ws + WS_EHI);
  unsigned short* e_lo = (unsigned short*)(ws + WS_ELO);
  float* ws_count = ws + WS_COUNT;
  float* ws_diff = ws + WS_DIFF;
  float* ws_n = ws + WS_N;
  float* ws_enorm = ws + WS_ENORM;
  unsigned long long* ws_pack = (unsigned long long*)(ws + WS_PACK);

  // d_out-aliased scratch (rewritten before readback):
  unsigned short* z_hi = (unsigned short*)(out + OUT_Q);
  unsigned short* z_lo = (unsigned short*)(out + OUT_Q + 2097152);
  float* embsum = out + OUT_NEWAVG;  // [e][d]

  prep_kernel<<<2186, 256, 0, stream>>>(z, emb, cs, z_hi, z_lo, e_hi, e_lo,
                                        ws_enorm, embsum, ws_pack, ws_count,
                                        ws_n);
  argmin_mfma_kernel<<<512, 256, 0, stream>>>(z_hi, z_lo, e_hi, e_lo, ws_enorm,
                                              ws_pack);
  gather_update_kernel<<<NROWS / 4, 256, 0, stream>>>(
      z, e_hi, e_lo, ws_pack, out + OUT_Q, out + OUT_IDX, embsum, ws_count,
      ws_diff);
  fin1_kernel<<<544, 256, 0, stream>>>(eavg, embsum, cs, ws_count, ws_n,
                                       ws_diff, out + OUT_NEWEMB,
                                       out + OUT_NEWCS, out + OUT_DIFF);
  fin2b_kernel<<<(DIMC * NEMB) / 256, 256, 0, stream>>>(
      cs, ws_count, ws_n, out + OUT_NEWEMB, out + OUT_NEWAVG);
}

// Round 3
// 384.877 us; speedup vs baseline: 1.1389x; 1.0475x over previous
//
#include <hip/hip_runtime.h>

// ---------------------------------------------------------------------------
// VectorQuantizer: z(16,32,32,256) fp32, embedding(256,8192), cluster_size(8192),
// embedding_avg(256,8192).
// Outputs (concat, fp32): quantize_st[4194304], diff[1], embed_ind[16384](as float),
// new_embedding[2097152], new_cluster_size[8192], new_embedding_avg[2097152]
//
// R8 = R7 + XCD-aware block swizzle in argmin (T1). R7 analysis: FETCH 529MB
// (ideal 24MB) because each block re-reads its 128KB z-tile 16x (once per nt)
// and the per-XCD z working set (64 blocks x 128KB = 8MB) thrashes the 4MB
// XCD L2 -> z re-reads are HBM-latency, too long for the 1-phase prefetch
// window -> MfmaUtil stuck at 41%. Fix: give each XCD a 2048-row z SLAB
// (2MB hi+lo, L2-resident) and stream e instead (16 same-XCD blocks share
// each e chunk in loose lockstep -> ~1 HBM fetch per e line). All loads
// become ~L2-latency, which the existing double-buffer hides.
//   xcd = bid&7 (dispatch round-robins XCDs), w = bid>>3,
//   row_tile = xcd*16 + (w&15), chunk = w>>4.
// Kernel body / LDS image / MFMA order identical to R7 -> bit-identical.
// All other kernels verbatim.
// Aliasing timeline:
//   OUT_Q:      z_hi/z_lo planes (prep) -> quantize_st (gather)
//   OUT_NEWAVG: embsum [e][d] zeroed (prep), scattered (gather), read (fin1),
//               -> new_embedding_avg (fin2b)
//   OUT_NEWEMB: new_embedding (fin1), read by fin2b
// ---------------------------------------------------------------------------

#define DIMC  256
#define NEMB  8192
#define NROWS 16384

// d_out offsets (float elements)
#define OUT_Q      0u
#define OUT_DIFF   4194304u
#define OUT_IDX    4194305u
#define OUT_NEWEMB 4210689u
#define OUT_NEWCS  6307841u
#define OUT_NEWAVG 6316033u

// d_ws offsets (float elements) — total 2146308 floats = 8.59 MB
#define WS_EHI    0u          // bf16[8192][256] transposed emb hi
#define WS_ELO    1048576u    // bf16[8192][256] transposed emb lo
#define WS_COUNT  2097152u    // [NEMB]
#define WS_DIFF   2105344u    // [1]
#define WS_N      2105345u    // [1]  (written by prep, closed-form)
#define WS_ENORM  2105346u    // [NEMB] exact ||e||^2
#define WS_PACK   2113540u    // u64[NROWS]; byte 8454160 % 16 == 0 (16-aligned)

typedef __attribute__((ext_vector_type(8))) short short8;
typedef __attribute__((ext_vector_type(4))) float f32x4;

// round-to-nearest-even fp32 -> bf16 split: x ~= hi + lo
__device__ inline void split_bf16(float x, unsigned short& h, unsigned short& l) {
  unsigned u = __float_as_uint(x);
  unsigned r = u + 0x7FFFu + ((u >> 16) & 1u);
  h = (unsigned short)(r >> 16);
  float hf = __uint_as_float((unsigned)h << 16);
  float lo = x - hf;
  unsigned u2 = __float_as_uint(lo);
  unsigned r2 = u2 + 0x7FFFu + ((u2 >> 16) & 1u);
  l = (unsigned short)(r2 >> 16);
}

__device__ inline float bf16_f(unsigned short u) {
  return __uint_as_float((unsigned)u << 16);
}

// ---------------------------------------------------------------------------
// Fused prep: [0,1024) z split | [1024,1536) emb transpose/split |
// [1536,2048) embsum zero | [2048,2176) exact enorm | [2176,2184) pack 0xFF |
// [2184] count+diff zero | [2185] sum(cs) -> n closed-form
__global__ __launch_bounds__(256) void prep_kernel(
    const float* __restrict__ z, const float* __restrict__ emb,
    const float* __restrict__ cs, unsigned short* __restrict__ z_hi,
    unsigned short* __restrict__ z_lo, unsigned short* __restrict__ e_hi,
    unsigned short* __restrict__ e_lo, float* __restrict__ enorm,
    float* __restrict__ embsum, unsigned long long* __restrict__ pack,
    float* __restrict__ count_diff, float* __restrict__ n_out) {
  const int b = blockIdx.x;
  const int t = threadIdx.x;
  __shared__ float tile[64][68];
  __shared__ float red[4][64];

  if (b < 1024) {
#pragma unroll
    for (int it = 0; it < 4; ++it) {
      const int idx = (b * 256 + t) + it * 262144;
      const float4 v = reinterpret_cast<const float4*>(z)[idx];
      ushort4 h, l;
      split_bf16(v.x, h.x, l.x);
      split_bf16(v.y, h.y, l.y);
      split_bf16(v.z, h.z, l.z);
      split_bf16(v.w, h.w, l.w);
      reinterpret_cast<ushort4*>(z_hi)[idx] = h;
      reinterpret_cast<ushort4*>(z_lo)[idx] = l;
    }
  } else if (b < 1536) {
    const int bb = b - 1024;
    const int n0 = (bb & 127) * 64;
    const int k0 = (bb >> 7) * 64;
    const int c4 = (t & 15) * 4;
    const int rr = t >> 4;
#pragma unroll
    for (int i = 0; i < 4; ++i) {
      const int kl = rr + i * 16;
      const float4 v = *reinterpret_cast<const float4*>(
          &emb[(size_t)(k0 + kl) * NEMB + n0 + c4]);
      *reinterpret_cast<float4*>(&tile[kl][c4]) = v;
    }
    __syncthreads();
#pragma unroll
    for (int i = 0; i < 4; ++i) {
      const int nr = rr + i * 16;
      float4 v;
      v.x = tile[c4 + 0][nr];
      v.y = tile[c4 + 1][nr];
      v.z = tile[c4 + 2][nr];
      v.w = tile[c4 + 3][nr];
      const size_t off = (size_t)(n0 + nr) * DIMC + k0 + c4;
      ushort4 h, l;
      split_bf16(v.x, h.x, l.x);
      split_bf16(v.y, h.y, l.y);
      split_bf16(v.z, h.z, l.z);
      split_bf16(v.w, h.w, l.w);
      *reinterpret_cast<ushort4*>(&e_hi[off]) = h;
      *reinterpret_cast<ushort4*>(&e_lo[off]) = l;
    }
  } else if (b < 2048) {
    const int bb = b - 1536;
    const float4 zero = {0.f, 0.f, 0.f, 0.f};
#pragma unroll
    for (int it = 0; it < 4; ++it)
      reinterpret_cast<float4*>(embsum)[bb * 1024 + t + it * 256] = zero;
  } else if (b < 2176) {
    // exact enorm, R2 summation order
    const int l = t & 63;
    const int dg = t >> 6;
    const int e = (b - 2048) * 64 + l;
    float s = 0.f;
#pragma unroll 8
    for (int d = dg * 64; d < dg * 64 + 64; ++d) {
      const float v = emb[(size_t)d * NEMB + e];
      s = fmaf(v, v, s);
    }
    red[dg][l] = s;
    __syncthreads();
    if (dg == 0) enorm[e] = red[0][l] + red[1][l] + red[2][l] + red[3][l];
  } else if (b < 2184) {
    const int bb = b - 2176;
    const uint4 ff = {~0u, ~0u, ~0u, ~0u};  // ws_pack is 16-aligned
#pragma unroll
    for (int it = 0; it < 4; ++it)
      reinterpret_cast<uint4*>(pack)[bb * 1024 + t + it * 256] = ff;
  } else if (b == 2184) {
    for (int i = t; i < 8193; i += 256) count_diff[i] = 0.f;  // count + diff
  } else {
    // n = 0.99*sum(cs) + 0.01*16384 (sum(count) == NROWS exactly)
    float s = 0.f;
#pragma unroll
    for (int i = 0; i < 32; ++i) s += cs[t + i * 256];
#pragma unroll
    for (int off = 32; off > 0; off >>= 1) s += __shfl_down(s, off, 64);
    if ((t & 63) == 0) red[0][t >> 6] = s;
    __syncthreads();
    if (t == 0)
      n_out[0] = 0.99f * (red[0][0] + red[0][1] + red[0][2] + red[0][3]) +
                 163.84f;
  }
}

// ---------------------------------------------------------------------------
// MFMA dist+argmin — R8: R7's double-buffered BK=32 pipeline + XCD swizzle.
// Block 256 thr = 4 waves, tile 128 rows x 128 codes, wave tile 64x64
// (4x4 of 16x16x32 mfma), 48 MFMA/wave/step, 128 steps, 1 barrier/step,
// single end-of-step vmcnt(0) drain (loads issued one full compute phase
// earlier). XCD x owns rows [2048x, 2048x+2048) (2MB hi+lo slab, L2-resident;
// z re-reads become L2 hits); e streams, shared by 16 same-XCD blocks.
// LDS half-buffer layout (za/eb): [128 rows][8 chunks][8 shorts], logical
// chunk L (0..3 hi, 4..7 lo) at physical L ^ (row&7). K-slice order == R4/R5
// -> bit-identical accumulation.
__global__ __launch_bounds__(256, 2) void argmin_mfma_kernel(
    const unsigned short* __restrict__ z_hi, const unsigned short* __restrict__ z_lo,
    const unsigned short* __restrict__ e_hi, const unsigned short* __restrict__ e_lo,
    const float* __restrict__ enorm, unsigned long long* __restrict__ pack) {
  __shared__ short za[16384];   // 2 x 16 KB
  __shared__ short eb[16384];   // 2 x 16 KB
  __shared__ float elds[2048];  // 8 KB: ||e||^2 for this code chunk
  const int tid = threadIdx.x;
  const int bid = blockIdx.x;
  // XCD swizzle: dispatcher round-robins blocks across 8 XCDs by bid&7.
  // row_tile = xcd*16 + (w&15)  -> each XCD owns a 2048-row z slab (2MB, L2).
  // chunk    = w>>4             -> all 4 e chunks stream per XCD, 16 blocks
  //                                share each chunk in loose lockstep.
  const int xcd = bid & 7;
  const int w = bid >> 3;
  const int r0 = (xcd * 16 + (w & 15)) * 128;
  const int ebase = (w >> 4) * 2048;
  const int tx = tid & 15;
  const int q = (tid >> 4) & 3;
  const int wave = tid >> 6;
  const int wm = wave & 1;   // row half
  const int wn = wave >> 1;  // col half

  // hi/lo planes are contiguous; fold select into an element offset.
  const unsigned zdel = (unsigned)(z_lo - z_hi);  // 4194304
  const unsigned edel = (unsigned)(e_lo - e_hi);  // 2097152

  // Staging role of this thread (constant across steps): for chunk
  // P = tid + it*256: row = (tid>>3) + it*32, phys pos p = tid&7,
  // logical chunk lp = p ^ (row&7)  (same for all it since row&7 == (tid>>3)&7).
  const int lp = (tid & 7) ^ ((tid >> 3) & 7);
  const unsigned sz = (lp & 4) ? zdel : 0u;
  const unsigned se = (lp & 4) ? edel : 0u;
  const unsigned dch8 = (unsigned)(lp & 3) * 8u;
  unsigned zo[4], eo[4];
#pragma unroll
  for (int it = 0; it < 4; ++it) {
    const int row_it = (tid >> 3) + it * 32;
    zo[it] = sz + (unsigned)(r0 + row_it) * 256u + dch8;
    eo[it] = se + (unsigned)(ebase + row_it) * 256u + dch8;
  }

  // Issue 8 global_load_lds for step sidx into buffer sidx&1.
  auto STAGE = [&](int sidx) {
    const unsigned k0s = (unsigned)(sidx & 7) * 32u;
    const unsigned eas = (unsigned)(sidx >> 3) * 32768u + k0s;
    const unsigned lb = (unsigned)(sidx & 1) * 8192u + (unsigned)tid * 8u;
#pragma unroll
    for (int it = 0; it < 4; ++it) {
      __builtin_amdgcn_global_load_lds(
          (const __attribute__((address_space(1))) unsigned int*)(z_hi + zo[it] + k0s),
          (__attribute__((address_space(3))) unsigned int*)&za[lb + it * 2048],
          16, 0, 0);
      __builtin_amdgcn_global_load_lds(
          (const __attribute__((address_space(1))) unsigned int*)(e_hi + eo[it] + eas),
          (__attribute__((address_space(3))) unsigned int*)&eb[lb + it * 2048],
          16, 0, 0);
    }
  };

  float rmin[4][4];
  int ridx[4][4];
#pragma unroll
  for (int i = 0; i < 4; ++i)
#pragma unroll
    for (int r = 0; r < 4; ++r) { rmin[i][r] = 3.4028235e38f; ridx[i][r] = 0; }

  // Prologue: loads for step 0 in flight, enorm chunk -> LDS, full drain.
  STAGE(0);
  {
    const float4 v0 = *reinterpret_cast<const float4*>(&enorm[ebase + tid * 8]);
    const float4 v1 =
        *reinterpret_cast<const float4*>(&enorm[ebase + tid * 8 + 4]);
    *reinterpret_cast<float4*>(&elds[tid * 8]) = v0;
    *reinterpret_cast<float4*>(&elds[tid * 8 + 4]) = v1;
  }
  __syncthreads();

  for (int nt = 0; nt < 16; ++nt) {
    f32x4 acc[4][4];
#pragma unroll
    for (int i = 0; i < 4; ++i)
#pragma unroll
      for (int j = 0; j < 4; ++j) acc[i][j] = (f32x4)0.0f;

    for (int k2 = 0; k2 < 8; ++k2) {
      const int s = nt * 8 + k2;
      // ---- issue prefetch for s+1 into the other buffer ----
      if (s < 127) STAGE(s + 1);

      // ---- compute on buffer s&1 (data drained at end of prev step) ----
      const short* zb = &za[(unsigned)(s & 1) * 8192u];
      const short* ebf = &eb[(unsigned)(s & 1) * 8192u];
      short8 ah[4], al[4], bh[4], bl[4];
#pragma unroll
      for (int i = 0; i < 4; ++i) {
        const int va = q ^ (tx & 7);
        const int rl = wm * 64 + i * 16 + tx;
        ah[i] = *reinterpret_cast<const short8*>(&zb[rl * 64 + va * 8]);
        al[i] = *reinterpret_cast<const short8*>(&zb[rl * 64 + (va ^ 4) * 8]);
        const int cl = wn * 64 + i * 16 + tx;
        bh[i] = *reinterpret_cast<const short8*>(&ebf[cl * 64 + va * 8]);
        bl[i] = *reinterpret_cast<const short8*>(&ebf[cl * 64 + (va ^ 4) * 8]);
      }
#pragma unroll
      for (int i = 0; i < 4; ++i)
#pragma unroll
        for (int j = 0; j < 4; ++j) {
          acc[i][j] = __builtin_amdgcn_mfma_f32_16x16x32_bf16(ah[i], bh[j],
                                                             acc[i][j], 0, 0, 0);
          acc[i][j] = __builtin_amdgcn_mfma_f32_16x16x32_bf16(ah[i], bl[j],
                                                             acc[i][j], 0, 0, 0);
          acc[i][j] = __builtin_amdgcn_mfma_f32_16x16x32_bf16(al[i], bh[j],
                                                             acc[i][j], 0, 0, 0);
        }

      // ---- end-of-step: drain prefetch (issued a full compute phase ago)
      //      + all LDS reads, then barrier. No mid-step drains. ----
      asm volatile("s_waitcnt vmcnt(0) lgkmcnt(0)" ::: "memory");
      __builtin_amdgcn_sched_barrier(0);
      __builtin_amdgcn_s_barrier();
      asm volatile("" ::: "memory");
    }

    // nt epilogue: score = ||e||^2 - 2*dot (enorm from LDS — no vmem).
#pragma unroll
    for (int j = 0; j < 4; ++j) {
      const int cidx = nt * 128 + wn * 64 + j * 16 + tx;
      const float en = elds[cidx];
      const int col = ebase + cidx;
#pragma unroll
      for (int i = 0; i < 4; ++i)
#pragma unroll
        for (int r = 0; r < 4; ++r) {
          const float sc = en - 2.0f * acc[i][j][r];
          if (sc < rmin[i][r]) { rmin[i][r] = sc; ridx[i][r] = col; }
        }
    }
  }

#pragma unroll
  for (int i = 0; i < 4; ++i)
#pragma unroll
    for (int r = 0; r < 4; ++r) {
      float v = rmin[i][r];
      int ix = ridx[i][r];
#pragma unroll
      for (int off = 1; off < 16; off <<= 1) {
        const float ov = __shfl_xor(v, off, 16);
        const int oi = __shfl_xor(ix, off, 16);
        if (ov < v || (ov == v && oi < ix)) { v = ov; ix = oi; }
      }
      if (tx == 0) {
        const unsigned int fb = __float_as_uint(v);
        const unsigned int sb = (fb & 0x80000000u) ? ~fb : (fb | 0x80000000u);
        const unsigned long long key =
            ((unsigned long long)sb << 13) | (unsigned long long)(unsigned)ix;
        atomicMin(&pack[r0 + wm * 64 + i * 16 + q * 4 + r], key);
      }
    }
}

// ---------------------------------------------------------------------------
// Gather quantize (reconstruct fp32 = hi+lo), extract index, diff partial,
// scatter embed_sum/count. 1 wave per row. (R4 verbatim)
__global__ __launch_bounds__(256) void gather_update_kernel(
    const float* __restrict__ z, const unsigned short* __restrict__ e_hi,
    const unsigned short* __restrict__ e_lo,
    const unsigned long long* __restrict__ pack, float* __restrict__ out_q,
    float* __restrict__ out_idx, float* __restrict__ embsum,
    float* __restrict__ count, float* __restrict__ diff_acc) {
  const int row = blockIdx.x * 4 + (threadIdx.x >> 6);
  const int lane = threadIdx.x & 63;
  const int e = (int)(pack[row] & 8191ULL);
  if (lane == 0) out_idx[row] = (float)e;
  const float4 zv =
      *reinterpret_cast<const float4*>(&z[(size_t)row * DIMC + lane * 4]);
  const ushort4 h =
      *reinterpret_cast<const ushort4*>(&e_hi[(size_t)e * DIMC + lane * 4]);
  const ushort4 l =
      *reinterpret_cast<const ushort4*>(&e_lo[(size_t)e * DIMC + lane * 4]);
  const float q0 = bf16_f(h.x) + bf16_f(l.x);
  const float q1 = bf16_f(h.y) + bf16_f(l.y);
  const float q2 = bf16_f(h.z) + bf16_f(l.z);
  const float q3 = bf16_f(h.w) + bf16_f(l.w);
  const float d0 = q0 - zv.x, d1 = q1 - zv.y, d2 = q2 - zv.z, d3 = q3 - zv.w;
  float4 st;
  st.x = zv.x + d0; st.y = zv.y + d1; st.z = zv.z + d2; st.w = zv.w + d3;
  *reinterpret_cast<float4*>(&out_q[(size_t)row * DIMC + lane * 4]) = st;

  atomicAdd(&embsum[(size_t)e * DIMC + lane * 4 + 0], zv.x);
  atomicAdd(&embsum[(size_t)e * DIMC + lane * 4 + 1], zv.y);
  atomicAdd(&embsum[(size_t)e * DIMC + lane * 4 + 2], zv.z);
  atomicAdd(&embsum[(size_t)e * DIMC + lane * 4 + 3], zv.w);

  float local = d0 * d0 + d1 * d1 + d2 * d2 + d3 * d3;
#pragma unroll
  for (int off = 32; off > 0; off >>= 1) local += __shfl_down(local, off, 64);

  __shared__ float dred[4];
  if (lane == 0) {
    dred[threadIdx.x >> 6] = local;
    atomicAdd(&count[e], 1.0f);
  }
  __syncthreads();
  if (threadIdx.x == 0)
    atomicAdd(diff_acc, dred[0] + dred[1] + dred[2] + dred[3]);
}

// ---------------------------------------------------------------------------
// fin1: blocks [0,512): new_embedding[d][e] = (0.99*eavg + 0.01*embsum[e][d])
// * (1/smoothed(e)) — transpose + EMA + divide, one pass. smoothed recomputed
// locally from cs/count + closed-form n (no cross-kernel reduction).
// blocks [512,544): new_cluster_size + diff finalize.
__global__ __launch_bounds__(256) void fin1_kernel(
    const float* __restrict__ eavg, const float* __restrict__ embsum,
    const float* __restrict__ cs, const float* __restrict__ count,
    const float* __restrict__ n_ptr, const float* __restrict__ diff_acc,
    float* __restrict__ out_emb, float* __restrict__ out_ncs,
    float* __restrict__ out_diff) {
  const int b = blockIdx.x;
  const int t = threadIdx.x;
  __shared__ float tile[64][68];
  __shared__ float rs[64];
  if (b < 512) {
    const int e0 = (b & 127) * 64;
    const int d0 = (b >> 7) * 64;
    const int c4 = (t & 15) * 4;
    const int rr = t >> 4;
    if (t < 64) {
      const float n = n_ptr[0];
      const float ncs = cs[e0 + t] * 0.99f + 0.01f * count[e0 + t];
      const float sm = (ncs + 1e-5f) / (n + 0.08192f) * n;
      rs[t] = 1.0f / sm;
    }
#pragma unroll
    for (int i = 0; i < 4; ++i) {
      const int er = rr + i * 16;
      const float4 v = *reinterpret_cast<const float4*>(
          &embsum[(size_t)(e0 + er) * DIMC + d0 + c4]);
      *reinterpret_cast<float4*>(&tile[er][c4]) = v;
    }
    __syncthreads();
#pragma unroll
    for (int i = 0; i < 4; ++i) {
      const int dr = rr + i * 16;
      const size_t g = (size_t)(d0 + dr) * NEMB + e0 + c4;
      const float4 av = *reinterpret_cast<const float4*>(&eavg[g]);
      float4 o;
      o.x = (av.x * 0.99f + 0.01f * tile[c4 + 0][dr]) * rs[c4 + 0];
      o.y = (av.y * 0.99f + 0.01f * tile[c4 + 1][dr]) * rs[c4 + 1];
      o.z = (av.z * 0.99f + 0.01f * tile[c4 + 2][dr]) * rs[c4 + 2];
      o.w = (av.w * 0.99f + 0.01f * tile[c4 + 3][dr]) * rs[c4 + 3];
      *reinterpret_cast<float4*>(&out_emb[g]) = o;
    }
  } else {
    const int g = (b - 512) * 256 + t;
    out_ncs[g] = cs[g] * 0.99f + 0.01f * count[g];
    if (g == 0) out_diff[0] = diff_acc[0] * (1.0f / 4194304.0f);
  }
}

// ---------------------------------------------------------------------------
// fin2b: new_embedding_avg[g] = new_embedding[g] * smoothed(e). Elementwise —
// overwrites embsum scratch (fully consumed by fin1). ~2 ulp vs direct.
__global__ __launch_bounds__(256) void fin2b_kernel(
    const float* __restrict__ cs, const float* __restrict__ count,
    const float* __restrict__ n_ptr, const float* __restrict__ out_emb,
    float* __restrict__ out_avg) {
  const int g = blockIdx.x * 256 + threadIdx.x;
  const int e = g & 8191;
  const float n = n_ptr[0];
  const float ncs = cs[e] * 0.99f + 0.01f * count[e];
  const float sm = (ncs + 1e-5f) / (n + 0.08192f) * n;
  out_avg[g] = out_emb[g] * sm;
}

// ---------------------------------------------------------------------------
extern "C" void kernel_launch(void* const* d_in, const int* in_sizes, int n_in,
                              void* d_out, int out_size, void* d_ws,
                              size_t ws_size, hipStream_t stream) {
  const float* z = (const float*)d_in[0];
  const float* emb = (const float*)d_in[1];
  const float* cs = (const float*)d_in[2];
  const float* eavg = (const float*)d_in[3];
  float* out = (float*)d_out;
  float* ws = (float*)d_ws;

  unsigned short* e_hi = (unsigned short*)(ws + WS_EHI);
  unsigned short* e_lo = (unsigned short*)(ws + WS_ELO);
  float* ws_count = ws + WS_COUNT;
  float* ws_diff = ws + WS_DIFF;
  float* ws_n = ws + WS_N;
  float* ws_enorm = ws + WS_ENORM;
  unsigned long long* ws_pack = (unsigned long long*)(ws + WS_PACK);

  // d_out-aliased scratch (rewritten before readback):
  unsigned short* z_hi = (unsigned short*)(out + OUT_Q);
  unsigned short* z_lo = (unsigned short*)(out + OUT_Q + 2097152);
  float* embsum = out + OUT_NEWAVG;  // [e][d]

  prep_kernel<<<2186, 256, 0, stream>>>(z, emb, cs, z_hi, z_lo, e_hi, e_lo,
                                        ws_enorm, embsum, ws_pack, ws_count,
                                        ws_n);
  argmin_mfma_kernel<<<512, 256, 0, stream>>>(z_hi, z_lo, e_hi, e_lo, ws_enorm,
                                              ws_pack);
  gather_update_kernel<<<NROWS / 4, 256, 0, stream>>>(
      z, e_hi, e_lo, ws_pack, out + OUT_Q, out + OUT_IDX, embsum, ws_count,
      ws_diff);
  fin1_kernel<<<544, 256, 0, stream>>>(eavg, embsum, cs, ws_count, ws_n,
                                       ws_diff, out + OUT_NEWEMB,
                                       out + OUT_NEWCS, out + OUT_DIFF);
  fin2b_kernel<<<(DIMC * NEMB) / 256, 256, 0, stream>>>(
      cs, ws_count, ws_n, out + OUT_NEWEMB, out + OUT_NEWAVG);
}